// Round 1
// baseline (917.863 us; speedup 1.0000x reference)
//
#include <hip/hip_runtime.h>
#include <math.h>

// Problem constants: gts/preds [4, 8192, 3] fp32; out [4] fp32.
#define BB 4
#define NPTS 8192
#define THREADS 256
#define NQ_TOTAL (2 * BB * NPTS)       // 65536 (set,b,point) slots
#define QBLK 256                       // queries per block (4 waves x 64)
#define QPWV 64                        // queries per wave (2 B-frags)
#define CHUNK 2048                     // refs per LDS chunk (32 KB)
#define NCHUNK (NPTS / CHUNK)          // 4 chunks, double-buffered
#define NFRAG (CHUNK / 32)             // 64 A-frags per chunk
#define FBLK (2 * BB * (NPTS / QBLK))  // 256 blocks = 1 per CU, single pass

typedef __attribute__((ext_vector_type(8)))  short bf16x8;   // MFMA A/B frag
typedef __attribute__((ext_vector_type(16))) float f32x16;   // MFMA C/D frag

// ws layout:
//   refpack: NQ_TOTAL uint4  bf16 [x,y,z,rr_hi,rr_lo,1,1,0]       1 MiB
//   qpack:   NQ_TOTAL uint4  bf16 [-2x,-2y,-2z,1,1,qq_hi,qq_lo,0] 1 MiB
// MFMA dot = -2 q.r + rr + qq = |q-r|^2 on bf16-rounded points (numerics
// identical to the verified previous kernel).
//
// R16 restructure vs previous 3-kernel version:
//  - QPW 32->64: one A-frag ds_read feeds 2 MFMAs (2 query B-frags/wave)
//    -> LDS read traffic per output halves; kernel becomes MFMA-bound.
//  - SLICES 4->1: each block walks ALL refs via chunked double-buffered LDS
//    (2x32KB), T14 split staging (loads issued pre-compute, ds_write post)
//    -> no minpart round-trip, no merge kernel. Grid 256 = 1 block/CU.
//  - Fused epilogue: sqrt + wave/block reduce + 1 atomicAdd per block.
//  - Depth-2 frag prefetch (rolling 2-reg queue) covers ~120cy ds_read
//    latency at 1 wave/SIMD.

__device__ __forceinline__ unsigned short f2bf(float f) {   // RNE f32->bf16
    unsigned u = __float_as_uint(f);
    u += 0x7FFF + ((u >> 16) & 1);
    return (unsigned short)(u >> 16);
}
__device__ __forceinline__ float bf2f(unsigned short h) {
    return __uint_as_float(((unsigned)h) << 16);
}

// ---------------------------------------------------------------------------
// Kernel 1: round coords to bf16, build ref- and query-side fragments.
// Also zero-inits out[0..3] (stream-ordered before the atomicAdds).
// ---------------------------------------------------------------------------
__global__ __launch_bounds__(THREADS) void pack_kernel(
    const float* __restrict__ gts, const float* __restrict__ preds,
    uint4* __restrict__ refpack, uint4* __restrict__ qpack,
    float* __restrict__ out) {
    int idx = blockIdx.x * THREADS + threadIdx.x;
    if (idx < BB) out[idx] = 0.0f;
    if (idx >= NQ_TOTAL) return;
    int set  = idx / (BB * NPTS);          // 0 = gts, 1 = preds
    int pidx = idx - set * (BB * NPTS);
    const float* src = set ? preds : gts;
    unsigned short hx = f2bf(src[pidx * 3 + 0]);
    unsigned short hy = f2bf(src[pidx * 3 + 1]);
    unsigned short hz = f2bf(src[pidx * 3 + 2]);
    float fx = bf2f(hx), fy = bf2f(hy), fz = bf2f(hz);
    float rr = fmaf(fx, fx, fmaf(fy, fy, fz * fz));
    unsigned short hrr = f2bf(rr);
    unsigned short hlo = f2bf(rr - bf2f(hrr));
    const unsigned short ONE = 0x3F80;      // 1.0 bf16

    uint4 rv;                               // ref slots: [x,y,z,rrhi,rrlo,1,1,0]
    rv.x = (unsigned)hx  | ((unsigned)hy  << 16);
    rv.y = (unsigned)hz  | ((unsigned)hrr << 16);
    rv.z = (unsigned)hlo | ((unsigned)ONE << 16);
    rv.w = (unsigned)ONE;
    refpack[idx] = rv;

    unsigned short nx = f2bf(-2.0f * fx);   // exact (coords already bf16)
    unsigned short ny = f2bf(-2.0f * fy);
    unsigned short nz = f2bf(-2.0f * fz);
    uint4 qv;                               // query slots: [-2x,-2y,-2z,1,1,qqhi,qqlo,0]
    qv.x = (unsigned)nx  | ((unsigned)ny  << 16);
    qv.y = (unsigned)nz  | ((unsigned)ONE << 16);
    qv.z = (unsigned)ONE | ((unsigned)hrr << 16);
    qv.w = (unsigned)hlo;
    qpack[idx] = qv;
}

// Fold one pair of D frags into 4 independent min3 chains (4-deep each).
#define FOLD(P0, P1)                                              \
    _Pragma("unroll")                                             \
    for (int r = 0; r < 16; r += 4) {                             \
        c0 = fminf(fminf((P0)[r],     (P0)[r + 1]), c0);          \
        c1 = fminf(fminf((P0)[r + 2], (P0)[r + 3]), c1);          \
        c2 = fminf(fminf((P1)[r],     (P1)[r + 1]), c2);          \
        c3 = fminf(fminf((P1)[r + 2], (P1)[r + 3]), c3);          \
    }

// ---------------------------------------------------------------------------
// Kernel 2 (fused): per block = one (dir, b, 256-query group).
// Walks all 8192 refs in 4 double-buffered LDS chunks; each A-frag ds_read
// feeds 2 MFMAs (query cols w*64+0..31 and +32..63). Epilogue does
// sqrt + intra-wave sum + cross-wave sum + atomicAdd(out[b]).
// D layout (m74/m101): col = lane&31, row = (r&3)+8*(r>>2)+4*(lane>>5).
// ---------------------------------------------------------------------------
__global__ __launch_bounds__(THREADS) void chamfer_kernel(
    const uint4* __restrict__ refpack, const uint4* __restrict__ qpack,
    float* __restrict__ out) {
    __shared__ uint4 sref[2][CHUNK];       // 64 KB -> 1 block/CU

    int tid  = threadIdx.x;
    int blk  = blockIdx.x;                 // [0, 256)
    int dir  = blk >> 7;                   // 0: q=preds r=gts; 1: q=gts r=preds
    int b    = (blk >> 5) & 3;
    int qg   = blk & 31;                   // query group of 256
    int rset = dir;
    int qset = dir ^ 1;
    int wid  = tid >> 6;
    int lane = tid & 63;
    int l31  = lane & 31;

    const uint4* rgl = refpack + (size_t)(rset * BB + b) * NPTS;

    // Stage chunk 0 (latency exposed once; ~1 us).
    #pragma unroll
    for (int j = 0; j < CHUNK / THREADS; ++j)
        sref[0][j * THREADS + tid] = rgl[j * THREADS + tid];

    // Persistent query B-frags: lane l31 = query col; lanes 32-63 zero
    // (K slots 8-15 of B are 0, so the duplicated A upper half contributes 0).
    size_t qoff = (size_t)(qset * BB + b) * NPTS + (size_t)qg * QBLK
                + (size_t)wid * QPWV;
    bf16x8 bq0 = {0, 0, 0, 0, 0, 0, 0, 0};
    bf16x8 bq1 = {0, 0, 0, 0, 0, 0, 0, 0};
    if (lane < 32) {
        bq0 = ((const bf16x8*)qpack)[qoff + l31];
        bq1 = ((const bf16x8*)qpack)[qoff + 32 + l31];
    }
    __syncthreads();

    f32x16 zc;
    #pragma unroll
    for (int r = 0; r < 16; ++r) zc[r] = 0.0f;

    float c0 = 3.0e38f, c1 = 3.0e38f, c2 = 3.0e38f, c3 = 3.0e38f;

    for (int c = 0; c < NCHUNK; ++c) {
        // T14 split staging: issue next chunk's global loads NOW (they fly
        // under ~4k cycles of MFMA below), ds_write them after the compute.
        uint4 stg[CHUNK / THREADS];
        if (c + 1 < NCHUNK) {
            #pragma unroll
            for (int j = 0; j < CHUNK / THREADS; ++j)
                stg[j] = rgl[(c + 1) * CHUNK + j * THREADS + tid];
        }

        const bf16x8* sp = (const bf16x8*)sref[c & 1];

        // Depth-2 rolling prefetch queue: aq0 = frag t, aq1 = frag t+1.
        bf16x8 aq0 = sp[l31];
        bf16x8 aq1 = sp[32 + l31];
        f32x16 p0 = __builtin_amdgcn_mfma_f32_32x32x16_bf16(aq0, bq0, zc, 0, 0, 0);
        f32x16 p1 = __builtin_amdgcn_mfma_f32_32x32x16_bf16(aq0, bq1, zc, 0, 0, 0);
        aq0 = aq1;
        aq1 = sp[2 * 32 + l31];

        #pragma unroll 2
        for (int t = 1; t < NFRAG; ++t) {
            // Consume frag t (its ds_read issued 2 iters ago -> latency hidden).
            f32x16 d0 = __builtin_amdgcn_mfma_f32_32x32x16_bf16(aq0, bq0, zc, 0, 0, 0);
            f32x16 d1 = __builtin_amdgcn_mfma_f32_32x32x16_bf16(aq0, bq1, zc, 0, 0, 0);
            // Fold frag t-1's (long-landed) results while MFMAs are in flight.
            FOLD(p0, p1);
            aq0 = aq1;
            aq1 = sp[((t + 2) & (NFRAG - 1)) * 32 + l31];  // wrap reads harmless
            p0 = d0;
            p1 = d1;
        }
        FOLD(p0, p1);

        // Write the staged chunk into the other buffer (loads landed long ago).
        if (c + 1 < NCHUNK) {
            #pragma unroll
            for (int j = 0; j < CHUNK / THREADS; ++j)
                sref[(c + 1) & 1][j * THREADS + tid] = stg[j];
        }
        __syncthreads();
    }

    // Per-query global min: halves hold complementary ref-rows -> one shfl_xor.
    float m0 = fminf(c0, c1);
    m0 = fminf(m0, __shfl_xor(m0, 32, 64));
    float m1 = fminf(c2, c3);
    m1 = fminf(m1, __shfl_xor(m1, 32, 64));

    // lanes 0-31 own queries (w*64+l31) and (w*64+32+l31); lanes 32-63 are
    // duplicates -> zero them so the 32-wide sum tree counts each query once.
    float d = 0.0f;
    if (lane < 32)
        d = sqrtf(fmaxf(m0, 0.0f)) + sqrtf(fmaxf(m1, 0.0f));
    #pragma unroll
    for (int off = 16; off > 0; off >>= 1)
        d += __shfl_down(d, off, 64);

    // Cross-wave sum: reuse buf0 (chunk 3 used buf1; all waves past final
    // barrier before these writes).
    float* wsf = (float*)&sref[0][0];
    if (lane == 0) wsf[wid] = d;
    __syncthreads();
    if (tid == 0)
        atomicAdd(out + b, wsf[0] + wsf[1] + wsf[2] + wsf[3]);
}

extern "C" void kernel_launch(void* const* d_in, const int* in_sizes, int n_in,
                              void* d_out, int out_size, void* d_ws, size_t ws_size,
                              hipStream_t stream) {
    const float* gts   = (const float*)d_in[0];
    const float* preds = (const float*)d_in[1];
    float* out = (float*)d_out;

    char* ws = (char*)d_ws;
    uint4* refpack = (uint4*)ws;                                   // 1 MiB
    uint4* qpack   = (uint4*)(ws + (size_t)NQ_TOTAL * 16);         // 1 MiB

    pack_kernel<<<NQ_TOTAL / THREADS, THREADS, 0, stream>>>(
        gts, preds, refpack, qpack, out);

    chamfer_kernel<<<FBLK, THREADS, 0, stream>>>(refpack, qpack, out);
}

// Round 2
// 91.232 us; speedup vs baseline: 10.0608x; 10.0608x over previous
//
#include <hip/hip_runtime.h>
#include <math.h>

// Problem constants: gts/preds [4, 8192, 3] fp32; out [4] fp32.
#define BB 4
#define NPTS 8192
#define THREADS 256
#define NQ_TOTAL (2 * BB * NPTS)       // 65536 (set,b,point) slots
#define QBLK 256                       // queries per block (4 waves x 64)
#define QPWV 64                        // queries per wave (2 B-frags)
#define CHUNK 2048                     // refs per LDS chunk (32 KB)
#define NCHUNK (NPTS / CHUNK)          // 4 chunks, double-buffered
#define NFRAG (CHUNK / 32)             // 64 A-frags per chunk
#define GLDS_PER_WAVE (CHUNK / 4 / 64) // 8 global_load_lds per wave per chunk
#define FBLK (2 * BB * (NPTS / QBLK))  // 256 blocks = 1 per CU, single pass

typedef __attribute__((ext_vector_type(8)))  short bf16x8;   // MFMA A/B frag
typedef __attribute__((ext_vector_type(16))) float f32x16;   // MFMA C/D frag

// ws layout:
//   refpack: NQ_TOTAL uint4  bf16 [x,y,z,rr_hi,rr_lo,1,1,0]       1 MiB
//   qpack:   NQ_TOTAL uint4  bf16 [-2x,-2y,-2z,1,1,qq_hi,qq_lo,0] 1 MiB
// MFMA dot = -2 q.r + rr + qq = |q-r|^2 on bf16-rounded points (numerics
// identical to the verified 82.8us 3-kernel version).
//
// R17 (spill fix of R16): same fused single-pass structure, but
//  - staging via __builtin_amdgcn_global_load_lds width=16 (async DMA,
//    no stg[] register array, no chunk-long live ranges).  Linear LDS
//    dest per wave = exactly the DMA's base+lane*16 layout.
//  - __launch_bounds__(256, 1): grid is 256 = 1 block/CU = 1 wave/SIMD,
//    so allow up to 512 VGPRs -> no spill cliff (R16 hit VGPR=256 +
//    2.8 GB/dispatch of scratch traffic = the whole 871us).

__device__ __forceinline__ unsigned short f2bf(float f) {   // RNE f32->bf16
    unsigned u = __float_as_uint(f);
    u += 0x7FFF + ((u >> 16) & 1);
    return (unsigned short)(u >> 16);
}
__device__ __forceinline__ float bf2f(unsigned short h) {
    return __uint_as_float(((unsigned)h) << 16);
}

// ---------------------------------------------------------------------------
// Kernel 1: round coords to bf16, build ref- and query-side fragments.
// Also zero-inits out[0..3] (stream-ordered before the atomicAdds).
// ---------------------------------------------------------------------------
__global__ __launch_bounds__(THREADS) void pack_kernel(
    const float* __restrict__ gts, const float* __restrict__ preds,
    uint4* __restrict__ refpack, uint4* __restrict__ qpack,
    float* __restrict__ out) {
    int idx = blockIdx.x * THREADS + threadIdx.x;
    if (idx < BB) out[idx] = 0.0f;
    if (idx >= NQ_TOTAL) return;
    int set  = idx / (BB * NPTS);          // 0 = gts, 1 = preds
    int pidx = idx - set * (BB * NPTS);
    const float* src = set ? preds : gts;
    unsigned short hx = f2bf(src[pidx * 3 + 0]);
    unsigned short hy = f2bf(src[pidx * 3 + 1]);
    unsigned short hz = f2bf(src[pidx * 3 + 2]);
    float fx = bf2f(hx), fy = bf2f(hy), fz = bf2f(hz);
    float rr = fmaf(fx, fx, fmaf(fy, fy, fz * fz));
    unsigned short hrr = f2bf(rr);
    unsigned short hlo = f2bf(rr - bf2f(hrr));
    const unsigned short ONE = 0x3F80;      // 1.0 bf16

    uint4 rv;                               // ref slots: [x,y,z,rrhi,rrlo,1,1,0]
    rv.x = (unsigned)hx  | ((unsigned)hy  << 16);
    rv.y = (unsigned)hz  | ((unsigned)hrr << 16);
    rv.z = (unsigned)hlo | ((unsigned)ONE << 16);
    rv.w = (unsigned)ONE;
    refpack[idx] = rv;

    unsigned short nx = f2bf(-2.0f * fx);   // exact (coords already bf16)
    unsigned short ny = f2bf(-2.0f * fy);
    unsigned short nz = f2bf(-2.0f * fz);
    uint4 qv;                               // query slots: [-2x,-2y,-2z,1,1,qqhi,qqlo,0]
    qv.x = (unsigned)nx  | ((unsigned)ny  << 16);
    qv.y = (unsigned)nz  | ((unsigned)ONE << 16);
    qv.z = (unsigned)ONE | ((unsigned)hrr << 16);
    qv.w = (unsigned)hlo;
    qpack[idx] = qv;
}

// Fold one pair of D frags into 4 independent min3 chains (4-deep each).
#define FOLD(P0, P1)                                              \
    _Pragma("unroll")                                             \
    for (int r = 0; r < 16; r += 4) {                             \
        c0 = fminf(fminf((P0)[r],     (P0)[r + 1]), c0);          \
        c1 = fminf(fminf((P0)[r + 2], (P0)[r + 3]), c1);          \
        c2 = fminf(fminf((P1)[r],     (P1)[r + 1]), c2);          \
        c3 = fminf(fminf((P1)[r + 2], (P1)[r + 3]), c3);          \
    }

// Stage one 32KB chunk (2048 uint4) into sref[buf] via async DMA.
// Per wave: 8 x global_load_lds(16B): wave-uniform LDS base + lane*16,
// matching the per-lane global source rgl[... + lane].
#define STAGE(BUF, CBASE)                                                   \
    _Pragma("unroll")                                                       \
    for (int i = 0; i < GLDS_PER_WAVE; ++i)                                 \
        __builtin_amdgcn_global_load_lds(                                   \
            (const unsigned*)(rgl + (CBASE) + wid * 512 + i * 64 + lane),   \
            (unsigned*)&sref[BUF][wid * 512 + i * 64], 16, 0, 0);

// ---------------------------------------------------------------------------
// Kernel 2 (fused): per block = one (dir, b, 256-query group).
// Walks all 8192 refs in 4 double-buffered LDS chunks; each A-frag ds_read
// feeds 2 MFMAs (query cols w*64+0..31 and +32..63). Epilogue does
// sqrt + intra-wave sum + cross-wave sum + atomicAdd(out[b]).
// D layout (m74/m101): col = lane&31, row = (r&3)+8*(r>>2)+4*(lane>>5).
// ---------------------------------------------------------------------------
__global__ __launch_bounds__(THREADS, 1) void chamfer_kernel(
    const uint4* __restrict__ refpack, const uint4* __restrict__ qpack,
    float* __restrict__ out) {
    __shared__ uint4 sref[2][CHUNK];       // 64 KB -> 1 block/CU (grid=256)

    int tid  = threadIdx.x;
    int blk  = blockIdx.x;                 // [0, 256)
    int dir  = blk >> 7;                   // 0: q=preds r=gts; 1: q=gts r=preds
    int b    = (blk >> 5) & 3;
    int qg   = blk & 31;                   // query group of 256
    int rset = dir;
    int qset = dir ^ 1;
    int wid  = tid >> 6;
    int lane = tid & 63;
    int l31  = lane & 31;

    const uint4* rgl = refpack + (size_t)(rset * BB + b) * NPTS;

    // Stage chunk 0 (async; drained by the __syncthreads below).
    STAGE(0, 0);

    // Persistent query B-frags: lane l31 = query col; lanes 32-63 zero
    // (K slots 8-15 of B are 0, so the duplicated A upper half contributes 0).
    size_t qoff = (size_t)(qset * BB + b) * NPTS + (size_t)qg * QBLK
                + (size_t)wid * QPWV;
    bf16x8 bq0 = {0, 0, 0, 0, 0, 0, 0, 0};
    bf16x8 bq1 = {0, 0, 0, 0, 0, 0, 0, 0};
    if (lane < 32) {
        bq0 = ((const bf16x8*)qpack)[qoff + l31];
        bq1 = ((const bf16x8*)qpack)[qoff + 32 + l31];
    }
    __syncthreads();                       // drains vmcnt: chunk 0 ready

    f32x16 zc;
    #pragma unroll
    for (int r = 0; r < 16; ++r) zc[r] = 0.0f;

    float c0 = 3.0e38f, c1 = 3.0e38f, c2 = 3.0e38f, c3 = 3.0e38f;

    for (int c = 0; c < NCHUNK; ++c) {
        // Issue next chunk's DMA now; it flies under ~4k cycles of MFMA,
        // and the end-of-chunk __syncthreads drains it.
        if (c + 1 < NCHUNK) {
            STAGE((c + 1) & 1, (c + 1) * CHUNK);
        }

        const bf16x8* sp = (const bf16x8*)sref[c & 1];

        // Depth-2 rolling prefetch queue: aq0 = frag t, aq1 = frag t+1.
        bf16x8 aq0 = sp[l31];
        bf16x8 aq1 = sp[32 + l31];
        f32x16 p0 = __builtin_amdgcn_mfma_f32_32x32x16_bf16(aq0, bq0, zc, 0, 0, 0);
        f32x16 p1 = __builtin_amdgcn_mfma_f32_32x32x16_bf16(aq0, bq1, zc, 0, 0, 0);
        aq0 = aq1;
        aq1 = sp[2 * 32 + l31];

        #pragma unroll 2
        for (int t = 1; t < NFRAG; ++t) {
            // Consume frag t (its ds_read issued 2 iters ago -> latency hidden).
            f32x16 d0 = __builtin_amdgcn_mfma_f32_32x32x16_bf16(aq0, bq0, zc, 0, 0, 0);
            f32x16 d1 = __builtin_amdgcn_mfma_f32_32x32x16_bf16(aq0, bq1, zc, 0, 0, 0);
            // Fold frag t-1's (long-landed) results while MFMAs are in flight.
            FOLD(p0, p1);
            aq0 = aq1;
            aq1 = sp[((t + 2) & (NFRAG - 1)) * 32 + l31];  // wrap reads harmless
            p0 = d0;
            p1 = d1;
        }
        FOLD(p0, p1);

        // End of chunk: barrier drains the in-flight DMA (vmcnt) and all
        // ds_reads of this buffer before it is overwritten two chunks later.
        __syncthreads();
    }

    // Per-query global min: halves hold complementary ref-rows -> one shfl_xor.
    float m0 = fminf(c0, c1);
    m0 = fminf(m0, __shfl_xor(m0, 32, 64));
    float m1 = fminf(c2, c3);
    m1 = fminf(m1, __shfl_xor(m1, 32, 64));

    // lanes 0-31 own queries (w*64+l31) and (w*64+32+l31); lanes 32-63 are
    // duplicates -> zero them so the 32-wide sum tree counts each query once.
    float d = 0.0f;
    if (lane < 32)
        d = sqrtf(fmaxf(m0, 0.0f)) + sqrtf(fmaxf(m1, 0.0f));
    #pragma unroll
    for (int off = 16; off > 0; off >>= 1)
        d += __shfl_down(d, off, 64);

    // Cross-wave sum: reuse buf0 (all compute done past the final barrier).
    float* wsf = (float*)&sref[0][0];
    if (lane == 0) wsf[wid] = d;
    __syncthreads();
    if (tid == 0)
        atomicAdd(out + b, wsf[0] + wsf[1] + wsf[2] + wsf[3]);
}

extern "C" void kernel_launch(void* const* d_in, const int* in_sizes, int n_in,
                              void* d_out, int out_size, void* d_ws, size_t ws_size,
                              hipStream_t stream) {
    const float* gts   = (const float*)d_in[0];
    const float* preds = (const float*)d_in[1];
    float* out = (float*)d_out;

    char* ws = (char*)d_ws;
    uint4* refpack = (uint4*)ws;                                   // 1 MiB
    uint4* qpack   = (uint4*)(ws + (size_t)NQ_TOTAL * 16);         // 1 MiB

    pack_kernel<<<NQ_TOTAL / THREADS, THREADS, 0, stream>>>(
        gts, preds, refpack, qpack, out);

    chamfer_kernel<<<FBLK, THREADS, 0, stream>>>(refpack, qpack, out);
}

// Round 3
// 74.372 us; speedup vs baseline: 12.3415x; 1.2267x over previous
//
#include <hip/hip_runtime.h>
#include <math.h>

// Problem constants: gts/preds [4, 8192, 3] fp32; out [4] fp32.
#define BB 4
#define NPTS 8192
#define THREADS 512                    // 8 waves/block
#define NQ_TOTAL (2 * BB * NPTS)       // 65536 (set,b,point) slots
#define QBLK 256                       // queries per block (8 waves x 32)
#define QPWV 32                        // queries per wave (1 B-frag)
#define CHUNK 2048                     // refs per LDS chunk (32 KB)
#define NCHUNK (NPTS / CHUNK)          // 4 chunks, double-buffered
#define NFRAG (CHUNK / 32)             // 64 A-frags per chunk
#define GLDS_PER_WAVE (CHUNK / 8 / 64) // 4 global_load_lds per wave per chunk
#define FBLK (2 * BB * (NPTS / QBLK))  // 256 blocks = 1 per CU, single pass

typedef __attribute__((ext_vector_type(8)))  short bf16x8;   // MFMA A/B frag
typedef __attribute__((ext_vector_type(16))) float f32x16;   // MFMA C/D frag

// ws layout:
//   refpack: NQ_TOTAL uint4  bf16 [x,y,z,rr_hi,rr_lo,1,1,0]       1 MiB
//   qpack:   NQ_TOTAL uint4  bf16 [-2x,-2y,-2z,1,1,qq_hi,qq_lo,0] 1 MiB
// MFMA dot = -2 q.r + rr + qq = |q-r|^2 on bf16-rounded points (numerics
// identical to the verified versions; absmax has been 0.0 throughout).
//
// R18 (occupancy fix of R17): R17 was latency-bound at 1 wave/SIMD
// (MfmaUtil 15% = exactly the 6.9us MFMA-pipe floor inside a 40.5us
// kernel; every stall exposed).  Same fused single-pass structure, but:
//  - 512 threads = 8 waves/block -> 2 waves/SIMD (m114: MFMA+VALU
//    overlap across waves), QPWV 32 (1 B-frag, 1 MFMA per A-frag read).
//    Total MFMA work unchanged; LDS reads double but are far from their
//    ceiling (bank conflicts 0).
//  - fully-unrolled chunk body: ds_read offsets become immediates
//    (no per-iter address VALU), depth-2 MFMA pipeline keeps the fold
//    2 MFMAs behind its producer.

__device__ __forceinline__ unsigned short f2bf(float f) {   // RNE f32->bf16
    unsigned u = __float_as_uint(f);
    u += 0x7FFF + ((u >> 16) & 1);
    return (unsigned short)(u >> 16);
}
__device__ __forceinline__ float bf2f(unsigned short h) {
    return __uint_as_float(((unsigned)h) << 16);
}

// ---------------------------------------------------------------------------
// Kernel 1: round coords to bf16, build ref- and query-side fragments.
// Also zero-inits out[0..3] (stream-ordered before the atomicAdds).
// ---------------------------------------------------------------------------
__global__ __launch_bounds__(256) void pack_kernel(
    const float* __restrict__ gts, const float* __restrict__ preds,
    uint4* __restrict__ refpack, uint4* __restrict__ qpack,
    float* __restrict__ out) {
    int idx = blockIdx.x * 256 + threadIdx.x;
    if (idx < BB) out[idx] = 0.0f;
    if (idx >= NQ_TOTAL) return;
    int set  = idx / (BB * NPTS);          // 0 = gts, 1 = preds
    int pidx = idx - set * (BB * NPTS);
    const float* src = set ? preds : gts;
    unsigned short hx = f2bf(src[pidx * 3 + 0]);
    unsigned short hy = f2bf(src[pidx * 3 + 1]);
    unsigned short hz = f2bf(src[pidx * 3 + 2]);
    float fx = bf2f(hx), fy = bf2f(hy), fz = bf2f(hz);
    float rr = fmaf(fx, fx, fmaf(fy, fy, fz * fz));
    unsigned short hrr = f2bf(rr);
    unsigned short hlo = f2bf(rr - bf2f(hrr));
    const unsigned short ONE = 0x3F80;      // 1.0 bf16

    uint4 rv;                               // ref slots: [x,y,z,rrhi,rrlo,1,1,0]
    rv.x = (unsigned)hx  | ((unsigned)hy  << 16);
    rv.y = (unsigned)hz  | ((unsigned)hrr << 16);
    rv.z = (unsigned)hlo | ((unsigned)ONE << 16);
    rv.w = (unsigned)ONE;
    refpack[idx] = rv;

    unsigned short nx = f2bf(-2.0f * fx);   // exact (coords already bf16)
    unsigned short ny = f2bf(-2.0f * fy);
    unsigned short nz = f2bf(-2.0f * fz);
    uint4 qv;                               // query slots: [-2x,-2y,-2z,1,1,qqhi,qqlo,0]
    qv.x = (unsigned)nx  | ((unsigned)ny  << 16);
    qv.y = (unsigned)nz  | ((unsigned)ONE << 16);
    qv.z = (unsigned)ONE | ((unsigned)hrr << 16);
    qv.w = (unsigned)hlo;
    qpack[idx] = qv;
}

// Fold one D frag (16 f32) into 4 independent running-min chains.
// fminf(fminf(a,b),c) fuses to v_min3_f32 -> 8 min3, chain depth 2.
#define FOLD8(P)                                                   \
    c0 = fminf(fminf((P)[0],  (P)[1]),  c0);                       \
    c1 = fminf(fminf((P)[2],  (P)[3]),  c1);                       \
    c2 = fminf(fminf((P)[4],  (P)[5]),  c2);                       \
    c3 = fminf(fminf((P)[6],  (P)[7]),  c3);                       \
    c0 = fminf(fminf((P)[8],  (P)[9]),  c0);                       \
    c1 = fminf(fminf((P)[10], (P)[11]), c1);                       \
    c2 = fminf(fminf((P)[12], (P)[13]), c2);                       \
    c3 = fminf(fminf((P)[14], (P)[15]), c3);

// Stage one 32KB chunk (2048 uint4) into sref[buf] via async DMA.
// Per wave: 4 x global_load_lds(16B): wave-uniform LDS base + lane*16,
// matching the per-lane global source.
#define STAGE(BUF, CBASE)                                                   \
    _Pragma("unroll")                                                       \
    for (int i = 0; i < GLDS_PER_WAVE; ++i)                                 \
        __builtin_amdgcn_global_load_lds(                                   \
            (const unsigned*)(rgl + (CBASE) + wid * 256 + i * 64 + lane),   \
            (unsigned*)&sref[BUF][wid * 256 + i * 64], 16, 0, 0);

// ---------------------------------------------------------------------------
// Kernel 2 (fused): per block = one (dir, b, 256-query group), 8 waves.
// Each wave owns 32 query cols (one persistent B-frag) and walks all 8192
// refs in 4 double-buffered LDS chunks.  Epilogue: sqrt + intra-wave sum +
// cross-wave sum + atomicAdd(out[b]).
// D layout (m74/m101): col = lane&31, row = (r&3)+8*(r>>2)+4*(lane>>5).
// ---------------------------------------------------------------------------
__global__ __launch_bounds__(THREADS, 2) void chamfer_kernel(
    const uint4* __restrict__ refpack, const uint4* __restrict__ qpack,
    float* __restrict__ out) {
    __shared__ uint4 sref[2][CHUNK];       // 64 KB -> 1 block/CU (grid=256)

    int tid  = threadIdx.x;
    int blk  = blockIdx.x;                 // [0, 256)
    int dir  = blk >> 7;                   // 0: q=preds r=gts; 1: q=gts r=preds
    int b    = (blk >> 5) & 3;
    int qg   = blk & 31;                   // query group of 256
    int rset = dir;
    int qset = dir ^ 1;
    int wid  = tid >> 6;                   // 0..7
    int lane = tid & 63;
    int l31  = lane & 31;

    const uint4* rgl = refpack + (size_t)(rset * BB + b) * NPTS;

    // Stage chunk 0 (async; drained by the __syncthreads below).
    STAGE(0, 0);

    // Persistent query B-frag: lane l31 = query col; lanes 32-63 zero
    // (K slots 8-15 of B are 0, so the duplicated A upper half contributes 0).
    size_t qoff = (size_t)(qset * BB + b) * NPTS + (size_t)qg * QBLK
                + (size_t)wid * QPWV;
    bf16x8 bq = {0, 0, 0, 0, 0, 0, 0, 0};
    if (lane < 32) bq = ((const bf16x8*)qpack)[qoff + l31];
    __syncthreads();                       // drains vmcnt: chunk 0 ready

    f32x16 zc;
    #pragma unroll
    for (int r = 0; r < 16; ++r) zc[r] = 0.0f;

    float c0 = 3.0e38f, c1 = 3.0e38f, c2 = 3.0e38f, c3 = 3.0e38f;

    for (int c = 0; c < NCHUNK; ++c) {
        // Issue next chunk's DMA now; it flies under this chunk's MFMAs and
        // the end-of-chunk __syncthreads drains it.
        if (c + 1 < NCHUNK) {
            STAGE((c + 1) & 1, (c + 1) * CHUNK);
        }

        const bf16x8* sp = (const bf16x8*)sref[c & 1];

        // Depth-2 MFMA pipeline, fully unrolled (ds_read offsets = imm).
        bf16x8 a0 = sp[l31];
        bf16x8 a1 = sp[32 + l31];
        f32x16 p0 = __builtin_amdgcn_mfma_f32_32x32x16_bf16(a0, bq, zc, 0, 0, 0);
        f32x16 p1 = __builtin_amdgcn_mfma_f32_32x32x16_bf16(a1, bq, zc, 0, 0, 0);

        #pragma unroll
        for (int t = 2; t < NFRAG; t += 2) {
            bf16x8 n0 = sp[t * 32 + l31];
            bf16x8 n1 = sp[t * 32 + 32 + l31];
            f32x16 d0 = __builtin_amdgcn_mfma_f32_32x32x16_bf16(n0, bq, zc, 0, 0, 0);
            FOLD8(p0);                      // frag t-2: landed 2 MFMAs ago
            f32x16 d1 = __builtin_amdgcn_mfma_f32_32x32x16_bf16(n1, bq, zc, 0, 0, 0);
            FOLD8(p1);
            p0 = d0;                        // renamed away under full unroll
            p1 = d1;
        }
        FOLD8(p0);
        FOLD8(p1);

        // Barrier drains the in-flight DMA (vmcnt) and all ds_reads of this
        // buffer before it is overwritten next chunk.
        __syncthreads();
    }

    // Per-query global min: lane halves hold complementary ref-rows.
    float m = fminf(fminf(c0, c1), fminf(c2, c3));
    m = fminf(m, __shfl_xor(m, 32, 64));

    // lanes 0-31 own this wave's 32 queries; lanes 32-63 are duplicates.
    float d = 0.0f;
    if (lane < 32) d = sqrtf(fmaxf(m, 0.0f));
    #pragma unroll
    for (int off = 16; off > 0; off >>= 1)
        d += __shfl_down(d, off, 64);

    // Cross-wave sum: reuse buf0 (all compute done past the final barrier).
    float* wsf = (float*)&sref[0][0];
    if (lane == 0) wsf[wid] = d;
    __syncthreads();
    if (tid == 0) {
        float s = wsf[0] + wsf[1] + wsf[2] + wsf[3]
                + wsf[4] + wsf[5] + wsf[6] + wsf[7];
        atomicAdd(out + b, s);
    }
}

extern "C" void kernel_launch(void* const* d_in, const int* in_sizes, int n_in,
                              void* d_out, int out_size, void* d_ws, size_t ws_size,
                              hipStream_t stream) {
    const float* gts   = (const float*)d_in[0];
    const float* preds = (const float*)d_in[1];
    float* out = (float*)d_out;

    char* ws = (char*)d_ws;
    uint4* refpack = (uint4*)ws;                                   // 1 MiB
    uint4* qpack   = (uint4*)(ws + (size_t)NQ_TOTAL * 16);         // 1 MiB

    pack_kernel<<<NQ_TOTAL / 256, 256, 0, stream>>>(
        gts, preds, refpack, qpack, out);

    chamfer_kernel<<<FBLK, THREADS, 0, stream>>>(refpack, qpack, out);
}

// Round 4
// 72.500 us; speedup vs baseline: 12.6601x; 1.0258x over previous
//
#include <hip/hip_runtime.h>
#include <math.h>

// Problem constants: gts/preds [4, 8192, 3] fp32; out [4] fp32.
#define BB 4
#define NPTS 8192
#define THREADS 512                    // 8 waves/block
#define NQ_TOTAL (2 * BB * NPTS)       // 65536 (set,b,point) slots
#define QBLK 256                       // queries per block (8 waves x 32)
#define QPWV 32                        // queries per wave (1 B-frag)
#define CHUNK 2048                     // refs per LDS chunk (32 KB)
#define NCHUNK (NPTS / CHUNK)          // 4 chunks, double-buffered
#define NFRAG (CHUNK / 32)             // 64 A-frags per chunk
#define GLDS_PER_WAVE (CHUNK / 8 / 64) // 4 global_load_lds per wave per chunk
#define FBLK (2 * BB * (NPTS / QBLK))  // 256 blocks = 1 per CU, single pass

typedef __attribute__((ext_vector_type(8)))  short bf16x8;   // MFMA A/B frag
typedef __attribute__((ext_vector_type(16))) float f32x16;   // MFMA C/D frag

// ws layout:
//   refpack: NQ_TOTAL uint4  bf16 [x,y,z,rr_hi,rr_lo,1,1,0]       1 MiB
//   qpack:   NQ_TOTAL uint4  bf16 [-2x,-2y,-2z,1,1,qq_hi,qq_lo,0] 1 MiB
// MFMA dot = -2 q.r + rr + qq = |q-r|^2 on bf16-rounded points.
//
// R19 (latency fix of R18): R18 read each A-frag immediately before its
// MFMA; at 2 waves/SIMD the ~120cy ds_read latency needs ~5 steps of
// lookahead and the compiler only hoists ~1 -> ~60-80cy lgkmcnt stall per
// step (~20us).  This version restores an EXPLICIT depth-8 prefetch ring
// of named bf16x8 regs (rule-#20-safe: no runtime-indexed arrays) giving
// ~170cy of ds_read->MFMA distance, plus a depth-2 D pipeline so each
// fold consumes a result issued 2 MFMAs earlier.

__device__ __forceinline__ unsigned short f2bf(float f) {   // RNE f32->bf16
    unsigned u = __float_as_uint(f);
    u += 0x7FFF + ((u >> 16) & 1);
    return (unsigned short)(u >> 16);
}
__device__ __forceinline__ float bf2f(unsigned short h) {
    return __uint_as_float(((unsigned)h) << 16);
}

// ---------------------------------------------------------------------------
// Kernel 1: round coords to bf16, build ref- and query-side fragments.
// Also zero-inits out[0..3] (stream-ordered before the atomicAdds).
// ---------------------------------------------------------------------------
__global__ __launch_bounds__(256) void pack_kernel(
    const float* __restrict__ gts, const float* __restrict__ preds,
    uint4* __restrict__ refpack, uint4* __restrict__ qpack,
    float* __restrict__ out) {
    int idx = blockIdx.x * 256 + threadIdx.x;
    if (idx < BB) out[idx] = 0.0f;
    if (idx >= NQ_TOTAL) return;
    int set  = idx / (BB * NPTS);          // 0 = gts, 1 = preds
    int pidx = idx - set * (BB * NPTS);
    const float* src = set ? preds : gts;
    unsigned short hx = f2bf(src[pidx * 3 + 0]);
    unsigned short hy = f2bf(src[pidx * 3 + 1]);
    unsigned short hz = f2bf(src[pidx * 3 + 2]);
    float fx = bf2f(hx), fy = bf2f(hy), fz = bf2f(hz);
    float rr = fmaf(fx, fx, fmaf(fy, fy, fz * fz));
    unsigned short hrr = f2bf(rr);
    unsigned short hlo = f2bf(rr - bf2f(hrr));
    const unsigned short ONE = 0x3F80;      // 1.0 bf16

    uint4 rv;                               // ref slots: [x,y,z,rrhi,rrlo,1,1,0]
    rv.x = (unsigned)hx  | ((unsigned)hy  << 16);
    rv.y = (unsigned)hz  | ((unsigned)hrr << 16);
    rv.z = (unsigned)hlo | ((unsigned)ONE << 16);
    rv.w = (unsigned)ONE;
    refpack[idx] = rv;

    unsigned short nx = f2bf(-2.0f * fx);   // exact (coords already bf16)
    unsigned short ny = f2bf(-2.0f * fy);
    unsigned short nz = f2bf(-2.0f * fz);
    uint4 qv;                               // query slots: [-2x,-2y,-2z,1,1,qqhi,qqlo,0]
    qv.x = (unsigned)nx  | ((unsigned)ny  << 16);
    qv.y = (unsigned)nz  | ((unsigned)ONE << 16);
    qv.z = (unsigned)ONE | ((unsigned)hrr << 16);
    qv.w = (unsigned)hlo;
    qpack[idx] = qv;
}

// Fold one D frag (16 f32) into 4 independent running-min chains.
// fminf(fminf(a,b),c) fuses to v_min3_f32 -> 8 min3, chain depth 2.
#define FOLD8(P)                                                   \
    c0 = fminf(fminf((P)[0],  (P)[1]),  c0);                       \
    c1 = fminf(fminf((P)[2],  (P)[3]),  c1);                       \
    c2 = fminf(fminf((P)[4],  (P)[5]),  c2);                       \
    c3 = fminf(fminf((P)[6],  (P)[7]),  c3);                       \
    c0 = fminf(fminf((P)[8],  (P)[9]),  c0);                       \
    c1 = fminf(fminf((P)[10], (P)[11]), c1);                       \
    c2 = fminf(fminf((P)[12], (P)[13]), c2);                       \
    c3 = fminf(fminf((P)[14], (P)[15]), c3);

// One pipeline step: consume ring slot AQ (frag F), refill it with frag
// F+8 (same chunk) if it exists, fold the D-frag from 2 steps ago.
#define STEP(AQ, FN, DO_LOAD)                                               \
    {                                                                       \
        f32x16 dn = __builtin_amdgcn_mfma_f32_32x32x16_bf16(AQ, bq, zc, 0, 0, 0); \
        if (DO_LOAD) AQ = sp[(FN) * 32 + l31];                              \
        FOLD8(pp);                                                          \
        pp = pc; pc = dn;                                                   \
    }

// Stage one 32KB chunk (2048 uint4) into sref[buf] via async DMA.
// Per wave: 4 x global_load_lds(16B): wave-uniform LDS base + lane*16,
// matching the per-lane global source.
#define STAGE(BUF, CBASE)                                                   \
    _Pragma("unroll")                                                       \
    for (int i = 0; i < GLDS_PER_WAVE; ++i)                                 \
        __builtin_amdgcn_global_load_lds(                                   \
            (const unsigned*)(rgl + (CBASE) + wid * 256 + i * 64 + lane),   \
            (unsigned*)&sref[BUF][wid * 256 + i * 64], 16, 0, 0);

// ---------------------------------------------------------------------------
// Kernel 2 (fused): per block = one (dir, b, 256-query group), 8 waves.
// Each wave owns 32 query cols (one persistent B-frag) and walks all 8192
// refs in 4 double-buffered LDS chunks.  Epilogue: sqrt + intra-wave sum +
// cross-wave sum + atomicAdd(out[b]).
// D layout (m74/m101): col = lane&31, row = (r&3)+8*(r>>2)+4*(lane>>5).
// ---------------------------------------------------------------------------
__global__ __launch_bounds__(THREADS, 2) void chamfer_kernel(
    const uint4* __restrict__ refpack, const uint4* __restrict__ qpack,
    float* __restrict__ out) {
    __shared__ uint4 sref[2][CHUNK];       // 64 KB -> 1 block/CU (grid=256)

    int tid  = threadIdx.x;
    int blk  = blockIdx.x;                 // [0, 256)
    int dir  = blk >> 7;                   // 0: q=preds r=gts; 1: q=gts r=preds
    int b    = (blk >> 5) & 3;
    int qg   = blk & 31;                   // query group of 256
    int rset = dir;
    int qset = dir ^ 1;
    int wid  = tid >> 6;                   // 0..7
    int lane = tid & 63;
    int l31  = lane & 31;

    const uint4* rgl = refpack + (size_t)(rset * BB + b) * NPTS;

    // Stage chunk 0 (async; drained by the __syncthreads below).
    STAGE(0, 0);

    // Persistent query B-frag: lane l31 = query col; lanes 32-63 zero
    // (K slots 8-15 of B are 0, so A's lane-32-63 half contributes 0 and
    // may hold garbage -- only lanes 0-31 of A matter).
    size_t qoff = (size_t)(qset * BB + b) * NPTS + (size_t)qg * QBLK
                + (size_t)wid * QPWV;
    bf16x8 bq = {0, 0, 0, 0, 0, 0, 0, 0};
    if (lane < 32) bq = ((const bf16x8*)qpack)[qoff + l31];
    __syncthreads();                       // drains vmcnt: chunk 0 ready

    f32x16 zc;
    #pragma unroll
    for (int r = 0; r < 16; ++r) zc[r] = 0.0f;

    float c0 = 3.0e38f, c1 = 3.0e38f, c2 = 3.0e38f, c3 = 3.0e38f;

    for (int c = 0; c < NCHUNK; ++c) {
        // Issue next chunk's DMA now; it flies under this chunk's MFMAs and
        // the end-of-chunk __syncthreads drains it.
        if (c + 1 < NCHUNK) {
            STAGE((c + 1) & 1, (c + 1) * CHUNK);
        }

        const bf16x8* sp = (const bf16x8*)sref[c & 1];

        // Fill the depth-8 prefetch ring (8 named regs, frags 0-7).
        bf16x8 a0 = sp[0 * 32 + l31];
        bf16x8 a1 = sp[1 * 32 + l31];
        bf16x8 a2 = sp[2 * 32 + l31];
        bf16x8 a3 = sp[3 * 32 + l31];
        bf16x8 a4 = sp[4 * 32 + l31];
        bf16x8 a5 = sp[5 * 32 + l31];
        bf16x8 a6 = sp[6 * 32 + l31];
        bf16x8 a7 = sp[7 * 32 + l31];

        // Prime the depth-2 D pipeline with +INF frags (fold = no-op).
        f32x16 pp, pc;
        #pragma unroll
        for (int r = 0; r < 16; ++r) { pp[r] = 3.0e38f; pc[r] = 3.0e38f; }

        // 8 macro-steps x 8 frags; all ds offsets compile-time after unroll.
        #pragma unroll
        for (int m = 0; m < NFRAG / 8; ++m) {
            const bool L = (m < NFRAG / 8 - 1);      // last octet: no refill
            STEP(a0, (m + 1) * 8 + 0, L);
            STEP(a1, (m + 1) * 8 + 1, L);
            STEP(a2, (m + 1) * 8 + 2, L);
            STEP(a3, (m + 1) * 8 + 3, L);
            STEP(a4, (m + 1) * 8 + 4, L);
            STEP(a5, (m + 1) * 8 + 5, L);
            STEP(a6, (m + 1) * 8 + 6, L);
            STEP(a7, (m + 1) * 8 + 7, L);
        }
        FOLD8(pp);                          // drain the D pipeline
        FOLD8(pc);

        // Barrier drains the in-flight DMA (vmcnt) and all ds_reads of this
        // buffer before it is overwritten next chunk.
        __syncthreads();
    }

    // Per-query global min: lane halves hold complementary ref-rows.
    float m = fminf(fminf(c0, c1), fminf(c2, c3));
    m = fminf(m, __shfl_xor(m, 32, 64));

    // lanes 0-31 own this wave's 32 queries; lanes 32-63 are duplicates.
    float d = 0.0f;
    if (lane < 32) d = sqrtf(fmaxf(m, 0.0f));
    #pragma unroll
    for (int off = 16; off > 0; off >>= 1)
        d += __shfl_down(d, off, 64);

    // Cross-wave sum: reuse buf0 (all compute done past the final barrier).
    float* wsf = (float*)&sref[0][0];
    if (lane == 0) wsf[wid] = d;
    __syncthreads();
    if (tid == 0) {
        float s = wsf[0] + wsf[1] + wsf[2] + wsf[3]
                + wsf[4] + wsf[5] + wsf[6] + wsf[7];
        atomicAdd(out + b, s);
    }
}

extern "C" void kernel_launch(void* const* d_in, const int* in_sizes, int n_in,
                              void* d_out, int out_size, void* d_ws, size_t ws_size,
                              hipStream_t stream) {
    const float* gts   = (const float*)d_in[0];
    const float* preds = (const float*)d_in[1];
    float* out = (float*)d_out;

    char* ws = (char*)d_ws;
    uint4* refpack = (uint4*)ws;                                   // 1 MiB
    uint4* qpack   = (uint4*)(ws + (size_t)NQ_TOTAL * 16);         // 1 MiB

    pack_kernel<<<NQ_TOTAL / 256, 256, 0, stream>>>(
        gts, preds, refpack, qpack, out);

    chamfer_kernel<<<FBLK, THREADS, 0, stream>>>(refpack, qpack, out);
}

// Round 5
// 72.487 us; speedup vs baseline: 12.6624x; 1.0002x over previous
//
#include <hip/hip_runtime.h>
#include <math.h>

// Problem constants: gts/preds [4, 8192, 3] fp32; out [4] fp32.
#define BB 4
#define NPTS 8192
#define THREADS 512                    // 8 waves/block
#define NQ_TOTAL (2 * BB * NPTS)       // 65536 (dir,b,point) slots
#define QBLK 512                       // queries per block (8 waves x 64)
#define QPWV 64                        // queries per wave (2 B-frags)
#define HALFN 4096                     // refs per block (2-way ref split)
#define CHUNK 2048                     // refs per LDS chunk (32 KB)
#define NCHUNK (HALFN / CHUNK)         // 2 chunks, double-buffered
#define NFRAG (CHUNK / 32)             // 64 A-frags per chunk
#define GLDS_PER_WAVE (CHUNK / 8 / 64) // 4 global_load_lds per wave per chunk
#define FBLK 256                       // 2 halves x 2 dir x 4 b x 16 qgroups

typedef __attribute__((ext_vector_type(8)))  short bf16x8;   // MFMA A/B frag
typedef __attribute__((ext_vector_type(16))) float f32x16;   // MFMA C/D frag

// ws layout:
//   refpack: NQ_TOTAL uint4  bf16 [x,y,z,rr_hi,rr_lo,1,1,0]       1 MiB
//   qpack:   NQ_TOTAL uint4  bf16 [-2x,-2y,-2z,1,1,qq_hi,qq_lo,0] 1 MiB
//   minpart: NQ_TOTAL uint (fp32-as-uint partial d^2 mins)        256 KiB
// MFMA dot = -2 q.r + rr + qq = |q-r|^2 on bf16-rounded points.
//
// R20 (LDS-traffic fix of R19): R19 was LDS-read-bound: QPWV=32 meant one
// ds_read_b128 per MFMA -> 2048 reads x 12cy = 10.2us/CU floor (vs MFMA
// 6.8us), realized at ~45% eff = ~23us.  This version:
//  - QPWV=64: each A-frag ds_read feeds 2 MFMAs (2 persistent B-frags per
//    wave) -> LDS floor halves to 5.1us; kernel becomes MFMA-bound.
//  - grid stays 256 (1 block/CU, 8 waves = 2/SIMD) by splitting refs 2-way;
//    per-query partial mins merge via uint atomicMin (values clamped >= 0
//    first: max(.,0) is monotone so clamp-before-min == clamp-after-min,
//    and nonneg-float bits are order-isomorphic to uint).
//  - small merge kernel (64 blocks): uint4 loads, sqrt, sum, atomicAdd.

__device__ __forceinline__ unsigned short f2bf(float f) {   // RNE f32->bf16
    unsigned u = __float_as_uint(f);
    u += 0x7FFF + ((u >> 16) & 1);
    return (unsigned short)(u >> 16);
}
__device__ __forceinline__ float bf2f(unsigned short h) {
    return __uint_as_float(((unsigned)h) << 16);
}

// ---------------------------------------------------------------------------
// Kernel 1: round coords to bf16, build ref- and query-side fragments.
// Also zero-inits out[0..3] and re-inits minpart to FLT_MAX (ws is poisoned
// by the harness every iteration).
// ---------------------------------------------------------------------------
__global__ __launch_bounds__(256) void pack_kernel(
    const float* __restrict__ gts, const float* __restrict__ preds,
    uint4* __restrict__ refpack, uint4* __restrict__ qpack,
    unsigned* __restrict__ minpart, float* __restrict__ out) {
    int idx = blockIdx.x * 256 + threadIdx.x;
    if (idx < BB) out[idx] = 0.0f;
    if (idx >= NQ_TOTAL) return;
    minpart[idx] = 0x7F7FFFFFu;            // FLT_MAX bits
    int set  = idx / (BB * NPTS);          // 0 = gts, 1 = preds
    int pidx = idx - set * (BB * NPTS);
    const float* src = set ? preds : gts;
    unsigned short hx = f2bf(src[pidx * 3 + 0]);
    unsigned short hy = f2bf(src[pidx * 3 + 1]);
    unsigned short hz = f2bf(src[pidx * 3 + 2]);
    float fx = bf2f(hx), fy = bf2f(hy), fz = bf2f(hz);
    float rr = fmaf(fx, fx, fmaf(fy, fy, fz * fz));
    unsigned short hrr = f2bf(rr);
    unsigned short hlo = f2bf(rr - bf2f(hrr));
    const unsigned short ONE = 0x3F80;      // 1.0 bf16

    uint4 rv;                               // ref slots: [x,y,z,rrhi,rrlo,1,1,0]
    rv.x = (unsigned)hx  | ((unsigned)hy  << 16);
    rv.y = (unsigned)hz  | ((unsigned)hrr << 16);
    rv.z = (unsigned)hlo | ((unsigned)ONE << 16);
    rv.w = (unsigned)ONE;
    refpack[idx] = rv;

    unsigned short nx = f2bf(-2.0f * fx);   // exact (coords already bf16)
    unsigned short ny = f2bf(-2.0f * fy);
    unsigned short nz = f2bf(-2.0f * fz);
    uint4 qv;                               // query slots: [-2x,-2y,-2z,1,1,qqhi,qqlo,0]
    qv.x = (unsigned)nx  | ((unsigned)ny  << 16);
    qv.y = (unsigned)nz  | ((unsigned)ONE << 16);
    qv.z = (unsigned)ONE | ((unsigned)hrr << 16);
    qv.w = (unsigned)hlo;
    qpack[idx] = qv;
}

// Fold one D frag into 4 independent running-min chains (v_min3 pairs).
#define FOLD8(P, X0, X1, X2, X3)                                   \
    X0 = fminf(fminf((P)[0],  (P)[1]),  X0);                       \
    X1 = fminf(fminf((P)[2],  (P)[3]),  X1);                       \
    X2 = fminf(fminf((P)[4],  (P)[5]),  X2);                       \
    X3 = fminf(fminf((P)[6],  (P)[7]),  X3);                       \
    X0 = fminf(fminf((P)[8],  (P)[9]),  X0);                       \
    X1 = fminf(fminf((P)[10], (P)[11]), X1);                       \
    X2 = fminf(fminf((P)[12], (P)[13]), X2);                       \
    X3 = fminf(fminf((P)[14], (P)[15]), X3);

// One pipeline step: 2 MFMAs consume ring slot AQ (frag F), refill it with
// frag F+8 (same chunk) if it exists, fold both D-frags from 2 steps ago.
#define STEP2(AQ, FN, DO_LOAD)                                              \
    {                                                                       \
        f32x16 dn0 = __builtin_amdgcn_mfma_f32_32x32x16_bf16(AQ, bq0, zc, 0, 0, 0); \
        f32x16 dn1 = __builtin_amdgcn_mfma_f32_32x32x16_bf16(AQ, bq1, zc, 0, 0, 0); \
        if (DO_LOAD) AQ = sp[(FN) * 32 + l31];                              \
        FOLD8(pp0, c0, c1, c2, c3);                                         \
        FOLD8(pp1, c4, c5, c6, c7);                                         \
        pp0 = pc0; pc0 = dn0;                                               \
        pp1 = pc1; pc1 = dn1;                                               \
    }

// Stage one 32KB chunk (2048 uint4) into sref[buf] via async DMA.
// Per wave: 4 x global_load_lds(16B): wave-uniform LDS base + lane*16.
#define STAGE(BUF, CBASE)                                                   \
    _Pragma("unroll")                                                       \
    for (int i = 0; i < GLDS_PER_WAVE; ++i)                                 \
        __builtin_amdgcn_global_load_lds(                                   \
            (const unsigned*)(rgl + (CBASE) + wid * 256 + i * 64 + lane),   \
            (unsigned*)&sref[BUF][wid * 256 + i * 64], 16, 0, 0);

// ---------------------------------------------------------------------------
// Kernel 2: per block = one (half, dir, b, 512-query group), 8 waves.
// Each wave owns 64 query cols (2 persistent B-frags) and walks 4096 refs
// in 2 double-buffered LDS chunks; each A-frag ds_read feeds 2 MFMAs.
// Epilogue: clamp >= 0, uint atomicMin into minpart (2 per lane 0-31).
// D layout (m74/m101): col = lane&31, row = (r&3)+8*(r>>2)+4*(lane>>5).
// ---------------------------------------------------------------------------
__global__ __launch_bounds__(THREADS, 2) void chamfer_kernel(
    const uint4* __restrict__ refpack, const uint4* __restrict__ qpack,
    unsigned* __restrict__ minpart) {
    __shared__ uint4 sref[2][CHUNK];       // 64 KB -> 1 block/CU (grid=256)

    int tid  = threadIdx.x;
    int blk  = blockIdx.x;                 // [0, 256)
    int half = blk >> 7;
    int dir  = (blk >> 6) & 1;             // 0: q=preds r=gts; 1: q=gts r=preds
    int b    = (blk >> 4) & 3;
    int qg   = blk & 15;                   // query group of 512
    int rset = dir;
    int qset = dir ^ 1;
    int wid  = tid >> 6;                   // 0..7
    int lane = tid & 63;
    int l31  = lane & 31;

    const uint4* rgl = refpack + (size_t)(rset * BB + b) * NPTS
                     + (size_t)half * HALFN;

    // Stage chunk 0 (async; drained by the __syncthreads below).
    STAGE(0, 0);

    // Persistent query B-frags: lane l31 = query col; lanes 32-63 zero
    // (K slots 8-15 of B are 0, so A's lane-32-63 half contributes 0 and
    // may hold garbage -- only lanes 0-31 of A matter).
    size_t qoff = (size_t)(qset * BB + b) * NPTS + (size_t)qg * QBLK
                + (size_t)wid * QPWV;
    bf16x8 bq0 = {0, 0, 0, 0, 0, 0, 0, 0};
    bf16x8 bq1 = {0, 0, 0, 0, 0, 0, 0, 0};
    if (lane < 32) {
        bq0 = ((const bf16x8*)qpack)[qoff + l31];
        bq1 = ((const bf16x8*)qpack)[qoff + 32 + l31];
    }
    __syncthreads();                       // drains vmcnt: chunk 0 ready

    f32x16 zc;
    #pragma unroll
    for (int r = 0; r < 16; ++r) zc[r] = 0.0f;

    float c0 = 3.0e38f, c1 = 3.0e38f, c2 = 3.0e38f, c3 = 3.0e38f;
    float c4 = 3.0e38f, c5 = 3.0e38f, c6 = 3.0e38f, c7 = 3.0e38f;

    for (int c = 0; c < NCHUNK; ++c) {
        // Prefetch next chunk's DMA; flies under this chunk's MFMAs.
        if (c + 1 < NCHUNK) {
            STAGE((c + 1) & 1, (c + 1) * CHUNK);
        }

        const bf16x8* sp = (const bf16x8*)sref[c & 1];

        // Fill the depth-8 prefetch ring (8 named regs, frags 0-7).
        bf16x8 a0 = sp[0 * 32 + l31];
        bf16x8 a1 = sp[1 * 32 + l31];
        bf16x8 a2 = sp[2 * 32 + l31];
        bf16x8 a3 = sp[3 * 32 + l31];
        bf16x8 a4 = sp[4 * 32 + l31];
        bf16x8 a5 = sp[5 * 32 + l31];
        bf16x8 a6 = sp[6 * 32 + l31];
        bf16x8 a7 = sp[7 * 32 + l31];

        // Prime the depth-2 D pipelines with +INF frags (fold = no-op).
        f32x16 pp0, pc0, pp1, pc1;
        #pragma unroll
        for (int r = 0; r < 16; ++r) {
            pp0[r] = 3.0e38f; pc0[r] = 3.0e38f;
            pp1[r] = 3.0e38f; pc1[r] = 3.0e38f;
        }

        // 8 macro-steps x 8 frags; all ds offsets compile-time after unroll.
        #pragma unroll
        for (int m = 0; m < NFRAG / 8; ++m) {
            const bool L = (m < NFRAG / 8 - 1);      // last octet: no refill
            STEP2(a0, (m + 1) * 8 + 0, L);
            STEP2(a1, (m + 1) * 8 + 1, L);
            STEP2(a2, (m + 1) * 8 + 2, L);
            STEP2(a3, (m + 1) * 8 + 3, L);
            STEP2(a4, (m + 1) * 8 + 4, L);
            STEP2(a5, (m + 1) * 8 + 5, L);
            STEP2(a6, (m + 1) * 8 + 6, L);
            STEP2(a7, (m + 1) * 8 + 7, L);
        }
        FOLD8(pp0, c0, c1, c2, c3);         // drain the D pipelines
        FOLD8(pc0, c0, c1, c2, c3);
        FOLD8(pp1, c4, c5, c6, c7);
        FOLD8(pc1, c4, c5, c6, c7);

        // Barrier drains in-flight DMA (vmcnt) and this buffer's ds_reads.
        __syncthreads();
    }

    // Per-query partial min: lane halves hold complementary ref-rows.
    float m0 = fminf(fminf(c0, c1), fminf(c2, c3));
    m0 = fminf(m0, __shfl_xor(m0, 32, 64));
    float m1 = fminf(fminf(c4, c5), fminf(c6, c7));
    m1 = fminf(m1, __shfl_xor(m1, 32, 64));

    // Clamp >= 0 then uint atomicMin (order-isomorphic for nonneg floats).
    size_t qid = (size_t)(dir * BB + b) * NPTS + (size_t)qg * QBLK
               + (size_t)wid * QPWV;
    if (lane < 32) {
        atomicMin(minpart + qid + l31,      __float_as_uint(fmaxf(m0, 0.0f)));
        atomicMin(minpart + qid + 32 + l31, __float_as_uint(fmaxf(m1, 0.0f)));
    }
}

// ---------------------------------------------------------------------------
// Kernel 3: merge — sqrt + sum + atomicAdd.  64 blocks x 256 thr, 4 queries
// per thread (uint4).  Each block's 1024 queries lie within one (dir,b).
// ---------------------------------------------------------------------------
__global__ __launch_bounds__(256) void merge_kernel(
    const unsigned* __restrict__ minpart, float* __restrict__ out) {
    int t  = blockIdx.x * 256 + threadIdx.x;       // uint4 index
    uint4 v = ((const uint4*)minpart)[t];
    float d = sqrtf(__uint_as_float(v.x)) + sqrtf(__uint_as_float(v.y))
            + sqrtf(__uint_as_float(v.z)) + sqrtf(__uint_as_float(v.w));
    int b = (blockIdx.x >> 3) & 3;                 // (blk*1024 >> 13) & 3

    #pragma unroll
    for (int off = 32; off > 0; off >>= 1)
        d += __shfl_down(d, off, 64);

    __shared__ float wsum[4];
    int lane = threadIdx.x & 63;
    int wid  = threadIdx.x >> 6;
    if (lane == 0) wsum[wid] = d;
    __syncthreads();
    if (threadIdx.x == 0)
        atomicAdd(out + b, wsum[0] + wsum[1] + wsum[2] + wsum[3]);
}

extern "C" void kernel_launch(void* const* d_in, const int* in_sizes, int n_in,
                              void* d_out, int out_size, void* d_ws, size_t ws_size,
                              hipStream_t stream) {
    const float* gts   = (const float*)d_in[0];
    const float* preds = (const float*)d_in[1];
    float* out = (float*)d_out;

    char* ws = (char*)d_ws;
    uint4*    refpack = (uint4*)ws;                                // 1 MiB
    uint4*    qpack   = (uint4*)(ws + (size_t)NQ_TOTAL * 16);      // 1 MiB
    unsigned* minpart = (unsigned*)(ws + (size_t)NQ_TOTAL * 32);   // 256 KiB

    pack_kernel<<<NQ_TOTAL / 256, 256, 0, stream>>>(
        gts, preds, refpack, qpack, minpart, out);

    chamfer_kernel<<<FBLK, THREADS, 0, stream>>>(refpack, qpack, minpart);

    merge_kernel<<<NQ_TOTAL / 4 / 256, 256, 0, stream>>>(minpart, out);
}

// Round 6
// 72.442 us; speedup vs baseline: 12.6704x; 1.0006x over previous
//
#include <hip/hip_runtime.h>
#include <math.h>

// Problem constants: gts/preds [4, 8192, 3] fp32; out [4] fp32.
#define BB 4
#define NPTS 8192
#define THREADS 512                    // 8 waves/block
#define NQ_TOTAL (2 * BB * NPTS)       // 65536 (dir,b,point) slots
#define QBLK 512                       // queries per block (8 waves x 64)
#define QPWV 64                        // queries per wave (2 B-frags)
#define QUARTN 2048                    // refs per block (4-way ref split)
#define CHUNK 2048                     // single LDS chunk (32 KB)
#define NFRAG (CHUNK / 32)             // 64 A-frags
#define GLDS_PER_WAVE (CHUNK / 8 / 64) // 4 global_load_lds per wave
#define FBLK 512                       // 4 quarters x 2 dir x 4 b x 16 qgroups

typedef __attribute__((ext_vector_type(8)))  short bf16x8;   // MFMA A/B frag
typedef __attribute__((ext_vector_type(16))) float f32x16;   // MFMA C/D frag

// ws layout:
//   refpack: NQ_TOTAL uint4  bf16 [x,y,z,rr_hi,rr_lo,1,1,0]       1 MiB
//   qpack:   NQ_TOTAL uint4  bf16 [-2x,-2y,-2z,1,1,qq_hi,qq_lo,0] 1 MiB
//   minpart: NQ_TOTAL uint (fp32-as-uint partial d^2 mins)        256 KiB
// MFMA dot = -2 q.r + rr + qq = |q-r|^2 on bf16-rounded points.
//
// R21 (occupancy x2 of R20): R19/R20 falsified the ILP and LDS-traffic
// theories (both neutral at chamfer ~24us vs 6.9us MFMA-pipe floor).  The
// only lever that has moved this kernel is waves/SIMD (R17 1w = 40.7us ->
// R18 2w = ~24us).  This version gets 4 waves/SIMD: single-buffered 32KB
// LDS chunk per block, ref split 4-way (atomicMin merge, already proven in
// R20), grid 512 = 2 blocks/CU co-resident.  Register machinery leaned out
// (depth-4 A-ring, fold right after MFMA -- per-wave stalls are covered by
// 3 sibling waves) to fit the 128-VGPR cap of __launch_bounds__(512, 4).

__device__ __forceinline__ unsigned short f2bf(float f) {   // RNE f32->bf16
    unsigned u = __float_as_uint(f);
    u += 0x7FFF + ((u >> 16) & 1);
    return (unsigned short)(u >> 16);
}
__device__ __forceinline__ float bf2f(unsigned short h) {
    return __uint_as_float(((unsigned)h) << 16);
}

// ---------------------------------------------------------------------------
// Kernel 1: round coords to bf16, build ref- and query-side fragments.
// Also zero-inits out[0..3] and re-inits minpart to FLT_MAX (ws is poisoned
// by the harness every iteration).
// ---------------------------------------------------------------------------
__global__ __launch_bounds__(256) void pack_kernel(
    const float* __restrict__ gts, const float* __restrict__ preds,
    uint4* __restrict__ refpack, uint4* __restrict__ qpack,
    unsigned* __restrict__ minpart, float* __restrict__ out) {
    int idx = blockIdx.x * 256 + threadIdx.x;
    if (idx < BB) out[idx] = 0.0f;
    if (idx >= NQ_TOTAL) return;
    minpart[idx] = 0x7F7FFFFFu;            // FLT_MAX bits
    int set  = idx / (BB * NPTS);          // 0 = gts, 1 = preds
    int pidx = idx - set * (BB * NPTS);
    const float* src = set ? preds : gts;
    unsigned short hx = f2bf(src[pidx * 3 + 0]);
    unsigned short hy = f2bf(src[pidx * 3 + 1]);
    unsigned short hz = f2bf(src[pidx * 3 + 2]);
    float fx = bf2f(hx), fy = bf2f(hy), fz = bf2f(hz);
    float rr = fmaf(fx, fx, fmaf(fy, fy, fz * fz));
    unsigned short hrr = f2bf(rr);
    unsigned short hlo = f2bf(rr - bf2f(hrr));
    const unsigned short ONE = 0x3F80;      // 1.0 bf16

    uint4 rv;                               // ref slots: [x,y,z,rrhi,rrlo,1,1,0]
    rv.x = (unsigned)hx  | ((unsigned)hy  << 16);
    rv.y = (unsigned)hz  | ((unsigned)hrr << 16);
    rv.z = (unsigned)hlo | ((unsigned)ONE << 16);
    rv.w = (unsigned)ONE;
    refpack[idx] = rv;

    unsigned short nx = f2bf(-2.0f * fx);   // exact (coords already bf16)
    unsigned short ny = f2bf(-2.0f * fy);
    unsigned short nz = f2bf(-2.0f * fz);
    uint4 qv;                               // query slots: [-2x,-2y,-2z,1,1,qqhi,qqlo,0]
    qv.x = (unsigned)nx  | ((unsigned)ny  << 16);
    qv.y = (unsigned)nz  | ((unsigned)ONE << 16);
    qv.z = (unsigned)ONE | ((unsigned)hrr << 16);
    qv.w = (unsigned)hlo;
    qpack[idx] = qv;
}

// Fold one D frag into 4 independent running-min chains (v_min3 pairs).
#define FOLD8(P, X0, X1, X2, X3)                                   \
    X0 = fminf(fminf((P)[0],  (P)[1]),  X0);                       \
    X1 = fminf(fminf((P)[2],  (P)[3]),  X1);                       \
    X2 = fminf(fminf((P)[4],  (P)[5]),  X2);                       \
    X3 = fminf(fminf((P)[6],  (P)[7]),  X3);                       \
    X0 = fminf(fminf((P)[8],  (P)[9]),  X0);                       \
    X1 = fminf(fminf((P)[10], (P)[11]), X1);                       \
    X2 = fminf(fminf((P)[12], (P)[13]), X2);                       \
    X3 = fminf(fminf((P)[14], (P)[15]), X3);

// One lean step: 2 MFMAs consume ring slot AQ (frag F), refill AQ with frag
// F+4 if it exists, fold both D-frags immediately (the dependent-use stall
// is covered by the 3 sibling waves on this SIMD).
#define STEP(AQ, FN, DO_LOAD)                                               \
    {                                                                       \
        f32x16 d0 = __builtin_amdgcn_mfma_f32_32x32x16_bf16(AQ, bq0, zc, 0, 0, 0); \
        f32x16 d1 = __builtin_amdgcn_mfma_f32_32x32x16_bf16(AQ, bq1, zc, 0, 0, 0); \
        if (DO_LOAD) AQ = sp[(FN) * 32 + l31];                              \
        FOLD8(d0, c0, c1, c2, c3);                                          \
        FOLD8(d1, c4, c5, c6, c7);                                          \
    }

// Stage the 32KB chunk (2048 uint4) into sref via async DMA.
// Per wave: 4 x global_load_lds(16B): wave-uniform LDS base + lane*16.
#define STAGE()                                                             \
    _Pragma("unroll")                                                       \
    for (int i = 0; i < GLDS_PER_WAVE; ++i)                                 \
        __builtin_amdgcn_global_load_lds(                                   \
            (const unsigned*)(rgl + wid * 256 + i * 64 + lane),             \
            (unsigned*)&sref[wid * 256 + i * 64], 16, 0, 0);

// ---------------------------------------------------------------------------
// Kernel 2: per block = one (quarter, dir, b, 512-query group), 8 waves.
// Each wave owns 64 query cols (2 persistent B-frags) and walks 2048 refs
// from a single staged LDS chunk; each A-frag ds_read feeds 2 MFMAs.
// Epilogue: clamp >= 0, uint atomicMin into minpart (2 per lane 0-31).
// D layout (m74/m101): col = lane&31, row = (r&3)+8*(r>>2)+4*(lane>>5).
// ---------------------------------------------------------------------------
__global__ __launch_bounds__(THREADS, 4) void chamfer_kernel(
    const uint4* __restrict__ refpack, const uint4* __restrict__ qpack,
    unsigned* __restrict__ minpart) {
    __shared__ uint4 sref[CHUNK];          // 32 KB -> 2 blocks/CU (grid=512)

    int tid  = threadIdx.x;
    int blk  = blockIdx.x;                 // [0, 512)
    int quart= blk >> 7;                   // ref quarter 0..3
    int dir  = (blk >> 6) & 1;             // 0: q=preds r=gts; 1: q=gts r=preds
    int b    = (blk >> 4) & 3;
    int qg   = blk & 15;                   // query group of 512
    int rset = dir;
    int qset = dir ^ 1;
    int wid  = tid >> 6;                   // 0..7
    int lane = tid & 63;
    int l31  = lane & 31;

    const uint4* rgl = refpack + (size_t)(rset * BB + b) * NPTS
                     + (size_t)quart * QUARTN;

    // Stage the chunk (async; drained by the __syncthreads below).
    STAGE();

    // Persistent query B-frags: lane l31 = query col; lanes 32-63 zero
    // (K slots 8-15 of B are 0, so A's lane-32-63 half contributes 0 and
    // may hold garbage -- only lanes 0-31 of A matter).
    size_t qoff = (size_t)(qset * BB + b) * NPTS + (size_t)qg * QBLK
                + (size_t)wid * QPWV;
    bf16x8 bq0 = {0, 0, 0, 0, 0, 0, 0, 0};
    bf16x8 bq1 = {0, 0, 0, 0, 0, 0, 0, 0};
    if (lane < 32) {
        bq0 = ((const bf16x8*)qpack)[qoff + l31];
        bq1 = ((const bf16x8*)qpack)[qoff + 32 + l31];
    }
    __syncthreads();                       // drains vmcnt: chunk ready

    f32x16 zc;
    #pragma unroll
    for (int r = 0; r < 16; ++r) zc[r] = 0.0f;

    float c0 = 3.0e38f, c1 = 3.0e38f, c2 = 3.0e38f, c3 = 3.0e38f;
    float c4 = 3.0e38f, c5 = 3.0e38f, c6 = 3.0e38f, c7 = 3.0e38f;

    const bf16x8* sp = (const bf16x8*)sref;

    // Depth-4 prefetch ring (4 named regs, frags 0-3).
    bf16x8 a0 = sp[0 * 32 + l31];
    bf16x8 a1 = sp[1 * 32 + l31];
    bf16x8 a2 = sp[2 * 32 + l31];
    bf16x8 a3 = sp[3 * 32 + l31];

    // 16 macro-steps x 4 frags; all ds offsets compile-time after unroll.
    #pragma unroll
    for (int m = 0; m < NFRAG / 4; ++m) {
        const bool L = (m < NFRAG / 4 - 1);          // last quartet: no refill
        STEP(a0, (m + 1) * 4 + 0, L);
        STEP(a1, (m + 1) * 4 + 1, L);
        STEP(a2, (m + 1) * 4 + 2, L);
        STEP(a3, (m + 1) * 4 + 3, L);
    }

    // Per-query partial min: lane halves hold complementary ref-rows.
    float m0 = fminf(fminf(c0, c1), fminf(c2, c3));
    m0 = fminf(m0, __shfl_xor(m0, 32, 64));
    float m1 = fminf(fminf(c4, c5), fminf(c6, c7));
    m1 = fminf(m1, __shfl_xor(m1, 32, 64));

    // Clamp >= 0 then uint atomicMin (order-isomorphic for nonneg floats).
    size_t qid = (size_t)(dir * BB + b) * NPTS + (size_t)qg * QBLK
               + (size_t)wid * QPWV;
    if (lane < 32) {
        atomicMin(minpart + qid + l31,      __float_as_uint(fmaxf(m0, 0.0f)));
        atomicMin(minpart + qid + 32 + l31, __float_as_uint(fmaxf(m1, 0.0f)));
    }
}

// ---------------------------------------------------------------------------
// Kernel 3: merge — sqrt + sum + atomicAdd.  64 blocks x 256 thr, 4 queries
// per thread (uint4).  Each block's 1024 queries lie within one (dir,b).
// ---------------------------------------------------------------------------
__global__ __launch_bounds__(256) void merge_kernel(
    const unsigned* __restrict__ minpart, float* __restrict__ out) {
    int t  = blockIdx.x * 256 + threadIdx.x;       // uint4 index
    uint4 v = ((const uint4*)minpart)[t];
    float d = sqrtf(__uint_as_float(v.x)) + sqrtf(__uint_as_float(v.y))
            + sqrtf(__uint_as_float(v.z)) + sqrtf(__uint_as_float(v.w));
    int b = (blockIdx.x >> 3) & 3;                 // (blk*1024 >> 13) & 3

    #pragma unroll
    for (int off = 32; off > 0; off >>= 1)
        d += __shfl_down(d, off, 64);

    __shared__ float wsum[4];
    int lane = threadIdx.x & 63;
    int wid  = threadIdx.x >> 6;
    if (lane == 0) wsum[wid] = d;
    __syncthreads();
    if (threadIdx.x == 0)
        atomicAdd(out + b, wsum[0] + wsum[1] + wsum[2] + wsum[3]);
}

extern "C" void kernel_launch(void* const* d_in, const int* in_sizes, int n_in,
                              void* d_out, int out_size, void* d_ws, size_t ws_size,
                              hipStream_t stream) {
    const float* gts   = (const float*)d_in[0];
    const float* preds = (const float*)d_in[1];
    float* out = (float*)d_out;

    char* ws = (char*)d_ws;
    uint4*    refpack = (uint4*)ws;                                // 1 MiB
    uint4*    qpack   = (uint4*)(ws + (size_t)NQ_TOTAL * 16);      // 1 MiB
    unsigned* minpart = (unsigned*)(ws + (size_t)NQ_TOTAL * 32);   // 256 KiB

    pack_kernel<<<NQ_TOTAL / 256, 256, 0, stream>>>(
        gts, preds, refpack, qpack, minpart, out);

    chamfer_kernel<<<FBLK, THREADS, 0, stream>>>(refpack, qpack, minpart);

    merge_kernel<<<NQ_TOTAL / 4 / 256, 256, 0, stream>>>(minpart, out);
}